// Round 1
// baseline (190.254 us; speedup 1.0000x reference)
//
#include <hip/hip_runtime.h>

// UnweightedHadamardMixing: out[b,o,h,w] = sum_i W[o,i] * x[b,i,h,w]
// with W = H64 / 8 (Sylvester Hadamard, in_ch=out_ch=base_dim=64).
// => out[:, :, h, w] = FWHT_64(x[:, :, h, w]) * 0.125
//
// x: [32, 64, 256, 256] f32  (512 MiB)   out: same shape (512 MiB)
// Memory-bound: ~1.07 GB HBM traffic, floor ~170 us @ 6.3 TB/s.
//
// One thread per (b, hw) pixel column:
//  - 64 coalesced dword loads (stride 65536 elems between channels,
//    consecutive lanes -> consecutive hw -> 256 B contiguous per wave)
//  - 6-stage in-register FWHT (384 add/sub), fully unrolled so the
//    64-float array stays in VGPRs (rule: no runtime indexing)
//  - 64 coalesced stores with *0.125 fold

constexpr int CH = 64;          // channels (in == out)
constexpr int HW = 256 * 256;   // pixels per (b, channel) plane = 65536

__global__ __launch_bounds__(256) void hadamard_mix_kernel(
    const float* __restrict__ x, float* __restrict__ out, unsigned total_pix)
{
    const unsigned t = blockIdx.x * blockDim.x + threadIdx.x;
    if (t >= total_pix) return;

    const unsigned b  = t >> 16;          // t / HW   (HW = 2^16)
    const unsigned hw = t & (HW - 1);     // t % HW
    const unsigned base = (b << 22) | hw; // b*CH*HW + hw  (CH*HW = 2^22)

    float v[CH];
#pragma unroll
    for (int i = 0; i < CH; ++i)
        v[i] = x[base + ((unsigned)i << 16)];

    // In-register fast Walsh-Hadamard transform (Sylvester / natural order):
    // for each stage s: (a, b) -> (a+b, a-b) over pairs (i, i+s).
#pragma unroll
    for (int s = 1; s < CH; s <<= 1) {
#pragma unroll
        for (int i = 0; i < CH; ++i) {
            if ((i & s) == 0) {
                const float a = v[i];
                const float c = v[i + s];
                v[i]     = a + c;
                v[i + s] = a - c;
            }
        }
    }

#pragma unroll
    for (int o = 0; o < CH; ++o)
        out[base + ((unsigned)o << 16)] = v[o] * 0.125f;  // 1/sqrt(64)
}

extern "C" void kernel_launch(void* const* d_in, const int* in_sizes, int n_in,
                              void* d_out, int out_size, void* d_ws, size_t ws_size,
                              hipStream_t stream)
{
    const float* x = (const float*)d_in[0];
    // d_in[1] is h_kernel; its values are the Hadamard matrix we exploit
    // structurally, so it is not read on-device.
    float* out = (float*)d_out;

    const unsigned total_pix = (unsigned)(in_sizes[0] / CH);  // 32 * 65536
    const int block = 256;
    const int grid  = (int)((total_pix + block - 1) / block); // 8192

    hipLaunchKernelGGL(hadamard_mix_kernel, dim3(grid), dim3(block), 0, stream,
                       x, out, total_pix);
}

// Round 3
// 188.884 us; speedup vs baseline: 1.0073x; 1.0073x over previous
//
#include <hip/hip_runtime.h>

// UnweightedHadamardMixing: out[b,o,h,w] = sum_i W[o,i] * x[b,i,h,w]
// with W = H64 / 8 (Sylvester Hadamard, 64x64) => per-pixel FWHT_64 * 0.125.
//
// x: [32, 64, 256, 256] f32 (512 MiB), out same. Memory-bound:
// 1.074 GB mandatory HBM traffic, floor ~170 us @ 6.3 TB/s mixed R/W.
//
// R3 = R2 with the compile fix: clang ext_vector float2 (native vector
// type) so __builtin_nontemporal_load/store accept the pointer.
//  - 8 B/lane (512 B/wave per instruction): 2x DRAM burst length per
//    channel-stream, half the VMEM instruction count vs R1.
//  - nontemporal: pure streaming data, no reuse.

typedef float v2f __attribute__((ext_vector_type(2)));

constexpr int CH = 64;
constexpr int HW = 256 * 256;           // 65536 pixels per (b,c) plane

__global__ __launch_bounds__(256) void hadamard_mix_kernel(
    const v2f* __restrict__ x, v2f* __restrict__ out, unsigned total_pairs)
{
    const unsigned t = blockIdx.x * blockDim.x + threadIdx.x;
    if (t >= total_pairs) return;

    // float2-pairs per batch-plane = HW/2 = 32768 = 2^15
    const unsigned b  = t >> 15;
    const unsigned hp = t & 0x7FFFu;
    // base in float2 units: b * CH * (HW/2) + hp ; CH*HW/2 = 2^21
    const unsigned base2 = (b << 21) | hp;

    v2f v[CH];
#pragma unroll
    for (int i = 0; i < CH; ++i)
        v[i] = __builtin_nontemporal_load(&x[base2 + ((unsigned)i << 15)]);

    // In-register FWHT (Sylvester order): stage s pairs (i, i+s) -> (a+b, a-b)
#pragma unroll
    for (int s = 1; s < CH; s <<= 1) {
#pragma unroll
        for (int i = 0; i < CH; ++i) {
            if ((i & s) == 0) {
                const v2f a = v[i];
                const v2f c = v[i + s];
                v[i]     = a + c;
                v[i + s] = a - c;
            }
        }
    }

#pragma unroll
    for (int o = 0; o < CH; ++o) {
        const v2f r = v[o] * 0.125f;    // 1/sqrt(64)
        __builtin_nontemporal_store(r, &out[base2 + ((unsigned)o << 15)]);
    }
}

extern "C" void kernel_launch(void* const* d_in, const int* in_sizes, int n_in,
                              void* d_out, int out_size, void* d_ws, size_t ws_size,
                              hipStream_t stream)
{
    const v2f* x = (const v2f*)d_in[0];
    // d_in[1] (h_kernel) is the Hadamard matrix, exploited structurally.
    v2f* out = (v2f*)d_out;

    const unsigned total_pairs = (unsigned)(in_sizes[0] / CH / 2);  // 1,048,576
    const int block = 256;
    const int grid  = (int)((total_pairs + block - 1) / block);     // 4096

    hipLaunchKernelGGL(hadamard_mix_kernel, dim3(grid), dim3(block), 0, stream,
                       x, out, total_pairs);
}